// Round 2
// baseline (1825.146 us; speedup 1.0000x reference)
//
#include <hip/hip_runtime.h>
#include <math.h>

#define N_TOK 16384
#define DIM   1024
#define DFF_  4096
#define NE    8
#define MAXTILES 264            // sum ceil(n_e/128) <= 8 + 32768/128 = 264
#define MAXSLOTS (MAXTILES*128) // 33792

typedef __attribute__((ext_vector_type(8))) __bf16 bf16x8;
typedef __attribute__((ext_vector_type(4))) float  f32x4;
typedef __attribute__((ext_vector_type(8))) unsigned short u16x8;

__device__ __forceinline__ unsigned short f2bf(float f) {
    union { float f; unsigned int u; } v; v.f = f;
    unsigned int u = v.u;
    unsigned int r = (u + 0x7fffu + ((u >> 16) & 1u)) >> 16;  // RNE
    return (unsigned short)r;
}

__device__ __forceinline__ void gl_lds16(const void* g, void* l) {
    __builtin_amdgcn_global_load_lds(
        (const __attribute__((address_space(1))) void*)g,
        (__attribute__((address_space(3))) void*)l, 16, 0, 0);
}

// ---------------- x fp32 -> bf16 (same layout) ----------------
__global__ __launch_bounds__(256)
void conv_x_kernel(const float* __restrict__ in, unsigned short* __restrict__ outp, int n8) {
    for (int i = blockIdx.x * 256 + threadIdx.x; i < n8; i += gridDim.x * 256) {
        const float4* pp = reinterpret_cast<const float4*>(in + (size_t)i * 8);
        float4 a = pp[0], b = pp[1];
        u16x8 o;
        o[0]=f2bf(a.x); o[1]=f2bf(a.y); o[2]=f2bf(a.z); o[3]=f2bf(a.w);
        o[4]=f2bf(b.x); o[5]=f2bf(b.y); o[6]=f2bf(b.z); o[7]=f2bf(b.w);
        *reinterpret_cast<u16x8*>(outp + (size_t)i * 8) = o;
    }
}

// ---------------- [E][R][C] fp32 -> [E][C][R] bf16 (transpose so B frags are K-contiguous) ----------------
__global__ __launch_bounds__(256)
void transpose_conv(const float* __restrict__ in, unsigned short* __restrict__ outp, int R, int C) {
    __shared__ float tile[32][33];
    size_t mat = (size_t)R * C;
    const float* src = in + (size_t)blockIdx.z * mat;
    unsigned short* dst = outp + (size_t)blockIdx.z * mat;
    int c0 = blockIdx.x * 32, r0 = blockIdx.y * 32;
    int tc = threadIdx.x & 31, tr = threadIdx.x >> 5;   // tr 0..7
#pragma unroll
    for (int i = 0; i < 4; ++i)
        tile[tr + i*8][tc] = src[(size_t)(r0 + tr + i*8) * C + (c0 + tc)];
    __syncthreads();
#pragma unroll
    for (int i = 0; i < 4; ++i) {
        int a = tr + i*8;
        dst[(size_t)(c0 + a) * R + (r0 + tc)] = f2bf(tile[tc][a]);
    }
}

// ---------------- gating: fp32 logits, top-2, softmax ----------------
__global__ __launch_bounds__(256)
void gate_kernel(const float* __restrict__ x, const float* __restrict__ gW,
                 const float* __restrict__ gb, float* __restrict__ outIdx,
                 int* __restrict__ tokE, float* __restrict__ tokW, int* __restrict__ counts) {
    int wave = threadIdx.x >> 6, lane = threadIdx.x & 63;
    int tok = blockIdx.x * 4 + wave;
    const float* xr = x + (size_t)tok * DIM;
    float p[NE];
#pragma unroll
    for (int e = 0; e < NE; ++e) p[e] = 0.f;
    for (int i = lane; i < DIM; i += 64) {
        float xi = xr[i];
        const float* g = gW + (size_t)i * NE;
#pragma unroll
        for (int e = 0; e < NE; ++e) p[e] += xi * g[e];
    }
#pragma unroll
    for (int off = 32; off > 0; off >>= 1) {
#pragma unroll
        for (int e = 0; e < NE; ++e) p[e] += __shfl_xor(p[e], off, 64);
    }
    if (lane == 0) {
        float v0 = -1e30f, v1 = -1e30f; int i0 = 0, i1 = 0;
#pragma unroll
        for (int e = 0; e < NE; ++e) {
            float l = p[e] + gb[e];
            if (l > v0)      { v1 = v0; i1 = i0; v0 = l; i0 = e; }
            else if (l > v1) { v1 = l; i1 = e; }
        }
        float e1 = expf(v1 - v0);
        float inv = 1.0f / (1.0f + e1);
        outIdx[tok*2]   = (float)i0;        // harness reads d_out as fp32
        outIdx[tok*2+1] = (float)i1;
        tokE[tok*2] = i0; tokE[tok*2+1] = i1;
        tokW[tok*2] = inv; tokW[tok*2+1] = e1 * inv;
        atomicAdd(&counts[i0], 1);
        atomicAdd(&counts[i1], 1);
    }
}

// ---------------- per-expert padded offsets + tile table ----------------
__global__ void offsets_kernel(const int* __restrict__ counts, int* __restrict__ P,
                               int* __restrict__ tileinfo) {
    if (threadIdx.x == 0 && blockIdx.x == 0) {
        int off = 0, tid = 0;
        for (int e = 0; e < NE; ++e) {
            P[e] = off;
            int c = counts[e];
            int nt = (c + 127) >> 7;
            for (int tt = 0; tt < nt; ++tt) {
                tileinfo[tid*4+0] = e;
                tileinfo[tid*4+1] = off + tt*128;
                int v = c - tt*128; if (v > 128) v = 128;
                tileinfo[tid*4+2] = v;
                tid++;
            }
            off += nt << 7;
        }
        for (; tid < MAXTILES; ++tid) tileinfo[tid*4+0] = -1;
    }
}

// ---------------- scatter tokens into per-expert row lists ----------------
__global__ __launch_bounds__(256)
void scatter_kernel(const int* __restrict__ tokE, const float* __restrict__ tokW,
                    const int* __restrict__ P, int* __restrict__ cursor,
                    int* __restrict__ rowlist, float* __restrict__ slotW) {
    int tk = blockIdx.x * 256 + threadIdx.x;
    if (tk >= N_TOK) return;
#pragma unroll
    for (int k = 0; k < 2; ++k) {
        int e = tokE[tk*2 + k];
        int pos = atomicAdd(&cursor[e], 1);
        int slot = P[e] + pos;
        rowlist[slot] = tk;
        slotW[slot]  = tokW[tk*2 + k];
    }
}

// ---------------- GEMM1: gathered x @ W1[e] + b1 -> gelu -> h (bf16) ----------------
// 128x128 tile, BK=64, 4 waves (2x2), 16x16x32 bf16 MFMA  (m97 structure)
__global__ __launch_bounds__(256, 2)
void moe_gemm1(const unsigned short* __restrict__ xb,
               const unsigned short* __restrict__ W1t,   // [E][DFF][DIM]
               const float* __restrict__ b1,             // [E][DFF]
               const int* __restrict__ tileinfo,
               const int* __restrict__ rowlist,
               unsigned short* __restrict__ h) {         // [MAXSLOTS][DFF]
    int rs = blockIdx.x;
    int e = tileinfo[rs*4];
    if (e < 0) return;
    int base   = tileinfo[rs*4+1];
    int nvalid = tileinfo[rs*4+2];
    int colBlk = blockIdx.y;                              // 0..31

    __shared__ unsigned short As[128*64];
    __shared__ unsigned short Bs[128*64];

    int t = threadIdx.x;
    int wave = t >> 6, lane = t & 63;
    int wr = wave >> 1, wc = wave & 1;
    int lr = lane >> 3;            // row within 8-row chunk
    int lk = (lane & 7) * 8;       // k element offset of this lane's 16B

    const unsigned short* aSrc[4];
    const unsigned short* bSrc[4];
#pragma unroll
    for (int i = 0; i < 4; ++i) {
        int r = i*32 + wave*8 + lr;
        int tok = (r < nvalid) ? rowlist[base + r] : rowlist[base];
        aSrc[i] = xb + (size_t)tok * DIM + lk;
        int cb = colBlk*128 + r;
        bSrc[i] = W1t + (size_t)e * DFF_ * DIM + (size_t)cb * DIM + lk;
    }

    f32x4 acc[4][4] = {};

    for (int kt = 0; kt < DIM/64; ++kt) {
        __syncthreads();
        int ko = kt * 64;
#pragma unroll
        for (int i = 0; i < 4; ++i) {
            gl_lds16(aSrc[i] + ko, &As[(i*32 + wave*8)*64]);
            gl_lds16(bSrc[i] + ko, &Bs[(i*32 + wave*8)*64]);
        }
        __syncthreads();
#pragma unroll
        for (int kk = 0; kk < 2; ++kk) {
            bf16x8 a[4], b[4];
#pragma unroll
            for (int m = 0; m < 4; ++m)
                a[m] = *reinterpret_cast<const bf16x8*>(&As[(wr*64 + m*16 + (lane&15))*64 + kk*32 + (lane>>4)*8]);
#pragma unroll
            for (int n = 0; n < 4; ++n)
                b[n] = *reinterpret_cast<const bf16x8*>(&Bs[(wc*64 + n*16 + (lane&15))*64 + kk*32 + (lane>>4)*8]);
#pragma unroll
            for (int m = 0; m < 4; ++m)
#pragma unroll
                for (int n = 0; n < 4; ++n)
                    acc[m][n] = __builtin_amdgcn_mfma_f32_16x16x32_bf16(a[m], b[n], acc[m][n], 0, 0, 0);
        }
    }

    float bv[4];
#pragma unroll
    for (int n = 0; n < 4; ++n)
        bv[n] = b1[(size_t)e*DFF_ + colBlk*128 + wc*64 + n*16 + (lane & 15)];
#pragma unroll
    for (int m = 0; m < 4; ++m) {
        int rbase = wr*64 + m*16 + (lane>>4)*4;
#pragma unroll
        for (int j = 0; j < 4; ++j) {
            int row = rbase + j;
            size_t hrow = (size_t)(base + row) * DFF_;
#pragma unroll
            for (int n = 0; n < 4; ++n) {
                int col = colBlk*128 + wc*64 + n*16 + (lane & 15);
                unsigned short val;
                if (row < nvalid) {
                    float v = acc[m][n][j] + bv[n];
                    v = 0.5f * v * (1.0f + erff(v * 0.70710678118654752f));  // exact gelu
                    val = f2bf(v);
                } else {
                    val = 0;  // zero pad rows so GEMM2 staging is clean
                }
                h[hrow + col] = val;
            }
        }
    }
}

// ---------------- GEMM2: h @ W2[e] + b2 -> weighted atomicAdd into out ----------------
__global__ __launch_bounds__(256, 2)
void moe_gemm2(const unsigned short* __restrict__ h,     // [MAXSLOTS][DFF]
               const unsigned short* __restrict__ W2t,   // [E][DIM][DFF]
               const float* __restrict__ b2,             // [E][DIM]
               const int* __restrict__ tileinfo,
               const int* __restrict__ rowlist,
               const float* __restrict__ slotW,
               float* __restrict__ outp) {               // [N_TOK][DIM]
    int rs = blockIdx.x;
    int e = tileinfo[rs*4];
    if (e < 0) return;
    int base   = tileinfo[rs*4+1];
    int nvalid = tileinfo[rs*4+2];
    int colBlk = blockIdx.y;                              // 0..7

    __shared__ unsigned short As[128*64];
    __shared__ unsigned short Bs[128*64];

    int t = threadIdx.x;
    int wave = t >> 6, lane = t & 63;
    int wr = wave >> 1, wc = wave & 1;
    int lr = lane >> 3;
    int lk = (lane & 7) * 8;

    const unsigned short* aSrc[4];
    const unsigned short* bSrc[4];
#pragma unroll
    for (int i = 0; i < 4; ++i) {
        int r = i*32 + wave*8 + lr;
        aSrc[i] = h + (size_t)(base + r) * DFF_ + lk;
        int cb = colBlk*128 + r;
        bSrc[i] = W2t + (size_t)e * DIM * DFF_ + (size_t)cb * DFF_ + lk;
    }

    f32x4 acc[4][4] = {};

    for (int kt = 0; kt < DFF_/64; ++kt) {
        __syncthreads();
        int ko = kt * 64;
#pragma unroll
        for (int i = 0; i < 4; ++i) {
            gl_lds16(aSrc[i] + ko, &As[(i*32 + wave*8)*64]);
            gl_lds16(bSrc[i] + ko, &Bs[(i*32 + wave*8)*64]);
        }
        __syncthreads();
#pragma unroll
        for (int kk = 0; kk < 2; ++kk) {
            bf16x8 a[4], b[4];
#pragma unroll
            for (int m = 0; m < 4; ++m)
                a[m] = *reinterpret_cast<const bf16x8*>(&As[(wr*64 + m*16 + (lane&15))*64 + kk*32 + (lane>>4)*8]);
#pragma unroll
            for (int n = 0; n < 4; ++n)
                b[n] = *reinterpret_cast<const bf16x8*>(&Bs[(wc*64 + n*16 + (lane&15))*64 + kk*32 + (lane>>4)*8]);
#pragma unroll
            for (int m = 0; m < 4; ++m)
#pragma unroll
                for (int n = 0; n < 4; ++n)
                    acc[m][n] = __builtin_amdgcn_mfma_f32_16x16x32_bf16(a[m], b[n], acc[m][n], 0, 0, 0);
        }
    }

    float bv[4];
#pragma unroll
    for (int n = 0; n < 4; ++n)
        bv[n] = b2[(size_t)e*DIM + colBlk*128 + wc*64 + n*16 + (lane & 15)];
#pragma unroll
    for (int m = 0; m < 4; ++m) {
        int rbase = wr*64 + m*16 + (lane>>4)*4;
#pragma unroll
        for (int j = 0; j < 4; ++j) {
            int row = rbase + j;
            if (row < nvalid) {
                int tok = rowlist[base + row];
                float w = slotW[base + row];
                size_t orow = (size_t)tok * DIM;
#pragma unroll
                for (int n = 0; n < 4; ++n) {
                    int col = colBlk*128 + wc*64 + n*16 + (lane & 15);
                    atomicAdd(&outp[orow + col], w * (acc[m][n][j] + bv[n]));
                }
            }
        }
    }
}

extern "C" void kernel_launch(void* const* d_in, const int* in_sizes, int n_in,
                              void* d_out, int out_size, void* d_ws, size_t ws_size,
                              hipStream_t stream) {
    const float* x  = (const float*)d_in[0];
    const float* gW = (const float*)d_in[1];
    const float* gb = (const float*)d_in[2];
    const float* W1 = (const float*)d_in[3];
    const float* b1 = (const float*)d_in[4];
    const float* W2 = (const float*)d_in[5];
    const float* b2 = (const float*)d_in[6];
    float* outp = (float*)d_out;

    // workspace layout (~458 MB)
    char* ws = (char*)d_ws;
    size_t off = 0;
    auto alloc = [&](size_t bytes) { void* p = ws + off; off += (bytes + 511) & ~(size_t)511; return p; };
    unsigned short* xb   = (unsigned short*)alloc((size_t)N_TOK * DIM * 2);
    unsigned short* W1t  = (unsigned short*)alloc((size_t)NE * DFF_ * DIM * 2);
    unsigned short* W2t  = (unsigned short*)alloc((size_t)NE * DIM * DFF_ * 2);
    unsigned short* hbuf = (unsigned short*)alloc((size_t)MAXSLOTS * DFF_ * 2);
    int*   rowlist = (int*)alloc(MAXSLOTS * 4);
    float* slotW   = (float*)alloc(MAXSLOTS * 4);
    int*   tokE    = (int*)alloc(N_TOK * 2 * 4);
    float* tokW    = (float*)alloc(N_TOK * 2 * 4);
    int*   meta    = (int*)alloc(8192);
    int* counts   = meta;        // 8
    int* cursor   = meta + 8;    // 8
    int* Parr     = meta + 16;   // 8
    int* tileinfo = meta + 32;   // 264*4

    // zero meta + output accumulator (d_out is poisoned before every timed call)
    hipMemsetAsync(meta, 0, 8192, stream);
    hipMemsetAsync(outp, 0, (size_t)N_TOK * DIM * sizeof(float), stream);

    conv_x_kernel<<<2048, 256, 0, stream>>>(x, xb, N_TOK * DIM / 8);
    transpose_conv<<<dim3(DFF_/32, DIM/32, NE), 256, 0, stream>>>(W1, W1t, DIM, DFF_);
    transpose_conv<<<dim3(DIM/32, DFF_/32, NE), 256, 0, stream>>>(W2, W2t, DFF_, DIM);

    gate_kernel<<<N_TOK/4, 256, 0, stream>>>(x, gW, gb, outp + (size_t)N_TOK * DIM,
                                             tokE, tokW, counts);
    offsets_kernel<<<1, 64, 0, stream>>>(counts, Parr, tileinfo);
    scatter_kernel<<<N_TOK/256, 256, 0, stream>>>(tokE, tokW, Parr, cursor, rowlist, slotW);

    moe_gemm1<<<dim3(MAXTILES, DFF_/128), 256, 0, stream>>>(xb, W1t, b1, tileinfo, rowlist, hbuf);
    moe_gemm2<<<dim3(MAXTILES, DIM/128), 256, 0, stream>>>(hbuf, W2t, b2, tileinfo, rowlist, slotW, outp);
}